// Round 2
// baseline (238.093 us; speedup 1.0000x reference)
//
#include <hip/hip_runtime.h>
#include <math.h>

// ws accumulator slots (floats): [0]=kp_sq_sum, [1]=c1, [2]=c2, [3]=f1, [4]=f2
#define BTILE 1024

__global__ void init_acc(float* __restrict__ acc) {
    int i = blockIdx.x * blockDim.x + threadIdx.x;
    if (i < 8) acc[i] = 0.0f;
}

__global__ __launch_bounds__(256) void kp_kernel(const float* __restrict__ a,
                                                 const float* __restrict__ b,
                                                 int n, float* __restrict__ acc) {
    int tid = threadIdx.x;
    float s = 0.0f;
    for (int i = tid; i < n; i += 256) {
        float d = a[i] - b[i];
        s = fmaf(d, d, s);
    }
    for (int off = 32; off > 0; off >>= 1) s += __shfl_down(s, off, 64);
    __shared__ float red[4];
    int lane = tid & 63, wid = tid >> 6;
    if (lane == 0) red[wid] = s;
    __syncthreads();
    if (tid == 0) atomicAdd(acc, red[0] + red[1] + red[2] + red[3]);
}

// A_PLANAR: A stored [3][An] per batch (batch stride 3*An). else [An][3].
// Same for B. Each block: APB A-points, SPLIT-way partition of the B scan.
template<bool A_PLANAR, bool B_PLANAR, int SPLIT>
__global__ __launch_bounds__(256) void chamfer_min_sum(
    const float* __restrict__ A, int An,
    const float* __restrict__ B, int Bn,
    float* __restrict__ acc)
{
    constexpr int APB = 256 / SPLIT;
    __shared__ __align__(16) float sb[3][BTILE];
    __shared__ float red[256];
    __shared__ float wsum[4];

    const int b = blockIdx.y;
    const float* __restrict__ Ab = A + (size_t)b * 3 * An;
    const float* __restrict__ Bb = B + (size_t)b * 3 * Bn;

    const int tid = threadIdx.x;
    const int al  = tid % APB;   // local A index
    const int sp  = tid / APB;   // which B-segment this thread scans
    const int p   = blockIdx.x * APB + al;
    const bool valid = p < An;

    float ax = 0.f, ay = 0.f, az = 0.f;
    if (valid) {
        if (A_PLANAR) { ax = Ab[p]; ay = Ab[An + p]; az = Ab[2 * An + p]; }
        else          { ax = Ab[3 * p]; ay = Ab[3 * p + 1]; az = Ab[3 * p + 2]; }
    }

    float best = 3.402823466e38f;

    for (int t0 = 0; t0 < Bn; t0 += BTILE) {
        const int tn = min(BTILE, Bn - t0);
        // ---- stage tile of B into LDS (planar x/y/z) ----
        if (B_PLANAR) {
            for (int j = tid; j < tn; j += 256) {
                sb[0][j] = Bb[t0 + j];
                sb[1][j] = Bb[Bn + t0 + j];
                sb[2][j] = Bb[2 * Bn + t0 + j];
            }
        } else {
            for (int j = tid; j < 3 * tn; j += 256) {
                int pt = j / 3, c = j - 3 * pt;
                sb[c][pt] = Bb[3 * t0 + j];
            }
        }
        __syncthreads();

        if (valid) {
            const int seg = (tn + SPLIT - 1) / SPLIT;
            int j = sp * seg;
            const int jend = min(j + seg, tn);
            // align to 4
            for (; j < jend && (j & 3); ++j) {
                float dx = ax - sb[0][j], dy = ay - sb[1][j], dz = az - sb[2][j];
                best = fminf(best, fmaf(dx, dx, fmaf(dy, dy, dz * dz)));
            }
            for (; j + 4 <= jend; j += 4) {
                float4 bx = *(const float4*)&sb[0][j];
                float4 by = *(const float4*)&sb[1][j];
                float4 bz = *(const float4*)&sb[2][j];
                float dx, dy, dz, d0, d1, d2, d3;
                dx = ax - bx.x; dy = ay - by.x; dz = az - bz.x;
                d0 = fmaf(dx, dx, fmaf(dy, dy, dz * dz));
                dx = ax - bx.y; dy = ay - by.y; dz = az - bz.y;
                d1 = fmaf(dx, dx, fmaf(dy, dy, dz * dz));
                dx = ax - bx.z; dy = ay - by.z; dz = az - bz.z;
                d2 = fmaf(dx, dx, fmaf(dy, dy, dz * dz));
                dx = ax - bx.w; dy = ay - by.w; dz = az - bz.w;
                d3 = fmaf(dx, dx, fmaf(dy, dy, dz * dz));
                best = fminf(best, fminf(fminf(d0, d1), fminf(d2, d3)));
            }
            for (; j < jend; ++j) {
                float dx = ax - sb[0][j], dy = ay - sb[1][j], dz = az - sb[2][j];
                best = fminf(best, fmaf(dx, dx, fmaf(dy, dy, dz * dz)));
            }
        }
        __syncthreads();
    }

    // ---- combine mins across the SPLIT B-segments ----
    red[sp * APB + al] = best;
    __syncthreads();
#pragma unroll
    for (int st = SPLIT / 2; st > 0; st >>= 1) {
        if (sp < st) {
            float o = red[(sp + st) * APB + al];
            if (o < best) best = o;
            red[sp * APB + al] = best;
        }
        __syncthreads();
    }

    float contrib = (sp == 0 && valid) ? best : 0.0f;
    for (int off = 32; off > 0; off >>= 1) contrib += __shfl_down(contrib, off, 64);
    int lane = tid & 63, wid = tid >> 6;
    if (lane == 0) wsum[wid] = contrib;
    __syncthreads();
    if (tid == 0) atomicAdd(acc, wsum[0] + wsum[1] + wsum[2] + wsum[3]);
}

__global__ void finalize_kernel(const float* __restrict__ acc, float* __restrict__ out,
                                float ikp, float ic1, float ic2, float if1, float if2) {
    out[0] = acc[0] * ikp + acc[1] * ic1 + acc[2] * ic2 + acc[3] * if1 + acc[4] * if2;
}

extern "C" void kernel_launch(void* const* d_in, const int* in_sizes, int n_in,
                              void* d_out, int out_size, void* d_ws, size_t ws_size,
                              hipStream_t stream) {
    const float* pred   = (const float*)d_in[0];
    const float* target = (const float*)d_in[1];
    const float* coarse = (const float*)d_in[2]; // [B,3,Nc]
    const float* fine   = (const float*)d_in[3]; // [B,3,Nf]
    const float* gt     = (const float*)d_in[4]; // [B,M,3]
    float* out = (float*)d_out;
    float* acc = (float*)d_ws;

    const int nkp = in_sizes[0];        // 240
    const int B   = nkp / 30;           // 8
    const int Nc  = in_sizes[2] / (3 * B);  // 1024
    const int Nf  = in_sizes[3] / (3 * B);  // 4096
    const int M   = in_sizes[4] / (3 * B);  // 4096

    init_acc<<<1, 64, 0, stream>>>(acc);
    kp_kernel<<<1, 256, 0, stream>>>(pred, target, nkp, acc + 0);

    constexpr int SPLIT = 4;
    constexpr int APB = 256 / SPLIT;    // 64 A-points per block

    // c1: A = coarse (planar), B = gt (interleaved)
    chamfer_min_sum<true, false, SPLIT>
        <<<dim3((Nc + APB - 1) / APB, B), 256, 0, stream>>>(coarse, Nc, gt, M, acc + 1);
    // c2: A = gt (interleaved), B = coarse (planar)
    chamfer_min_sum<false, true, SPLIT>
        <<<dim3((M + APB - 1) / APB, B), 256, 0, stream>>>(gt, M, coarse, Nc, acc + 2);
    // f1: A = fine (planar), B = gt (interleaved)
    chamfer_min_sum<true, false, SPLIT>
        <<<dim3((Nf + APB - 1) / APB, B), 256, 0, stream>>>(fine, Nf, gt, M, acc + 3);
    // f2: A = gt (interleaved), B = fine (planar)
    chamfer_min_sum<false, true, SPLIT>
        <<<dim3((M + APB - 1) / APB, B), 256, 0, stream>>>(gt, M, fine, Nf, acc + 4);

    finalize_kernel<<<1, 1, 0, stream>>>(acc, out,
        1.0f / nkp, 1.0f / (B * Nc), 1.0f / (B * M), 1.0f / (B * Nf), 1.0f / (B * M));
}

// Round 5
// 112.427 us; speedup vs baseline: 2.1178x; 2.1178x over previous
//
#include <hip/hip_runtime.h>
#include <math.h>

#define BTILE 1024
#define SPLIT 8
#define APB   32     // 256 / SPLIT : A-points per block
#define SEG   128    // BTILE / SPLIT : B-points per thread per tile

// min over b of |a-b|^2 = a2 + min over b of (b2 - 2 a.b).
// Stage planes {-2bx, -2by, -2bz, b2} in LDS -> 3 fma + 1 min per pair.
template<bool A_PLANAR, bool B_PLANAR>
__device__ __forceinline__ void chamfer_block(
    const float* __restrict__ A, int An,
    const float* __restrict__ B, int Bn,
    int lbid, float scale,
    float (&sb)[4][BTILE], float (&red)[256],
    float* __restrict__ wslot)
{
    const int bpb   = An / APB;          // blocks per batch
    const int batch = lbid / bpb;
    const int ablk  = lbid % bpb;
    const float* __restrict__ Ab = A + (size_t)batch * 3 * An;
    const float* __restrict__ Bb = B + (size_t)batch * 3 * Bn;

    const int tid = threadIdx.x;
    const int al  = tid & (APB - 1);
    const int sp  = tid >> 5;            // log2(APB)=5
    const int p   = ablk * APB + al;

    float ax, ay, az;
    if (A_PLANAR) { ax = Ab[p];     ay = Ab[An + p];  az = Ab[2*An + p]; }
    else          { ax = Ab[3*p];   ay = Ab[3*p + 1]; az = Ab[3*p + 2];  }
    const float a2 = fmaf(ax, ax, fmaf(ay, ay, az * az));

    float m0 = 3.402823466e38f, m1 = m0, m2 = m0, m3 = m0;

    const int NT = Bn / BTILE;
    for (int t = 0; t < NT; ++t) {
        const int t0 = t * BTILE;
        // ---- stage pre-scaled tile ----
        for (int k = tid; k < BTILE; k += 256) {
            float x, y, z;
            if (B_PLANAR) {
                x = Bb[t0 + k]; y = Bb[Bn + t0 + k]; z = Bb[2*Bn + t0 + k];
            } else {
                int base = 3 * (t0 + k);
                x = Bb[base]; y = Bb[base + 1]; z = Bb[base + 2];
            }
            sb[0][k] = -2.0f * x;
            sb[1][k] = -2.0f * y;
            sb[2][k] = -2.0f * z;
            sb[3][k] = fmaf(x, x, fmaf(y, y, z * z));
        }
        __syncthreads();

        const float4* __restrict__ px = (const float4*)&sb[0][sp * SEG];
        const float4* __restrict__ py = (const float4*)&sb[1][sp * SEG];
        const float4* __restrict__ pz = (const float4*)&sb[2][sp * SEG];
        const float4* __restrict__ pw = (const float4*)&sb[3][sp * SEG];
#pragma unroll 8
        for (int g = 0; g < SEG / 4; ++g) {
            float4 x = px[g], y = py[g], z = pz[g], w = pw[g];
            m0 = fminf(m0, fmaf(ax, x.x, fmaf(ay, y.x, fmaf(az, z.x, w.x))));
            m1 = fminf(m1, fmaf(ax, x.y, fmaf(ay, y.y, fmaf(az, z.y, w.y))));
            m2 = fminf(m2, fmaf(ax, x.z, fmaf(ay, y.z, fmaf(az, z.z, w.z))));
            m3 = fminf(m3, fmaf(ax, x.w, fmaf(ay, y.w, fmaf(az, z.w, w.w))));
        }
        __syncthreads();
    }
    float best = fminf(fminf(m0, m1), fminf(m2, m3));

    // ---- min across the SPLIT segments (same al, different sp) ----
    red[tid] = best;
    __syncthreads();
#pragma unroll
    for (int s = 128; s >= APB; s >>= 1) {
        if (tid < s) red[tid] = fminf(red[tid], red[tid + s]);
        __syncthreads();
    }

    // ---- per-A-point distance, scaled block partial ----
    if (tid < APB) {
        float d = fmaxf(0.0f, a2 + red[tid]) * scale;
#pragma unroll
        for (int off = APB / 2; off > 0; off >>= 1) d += __shfl_down(d, off, APB);
        if (tid == 0) *wslot = d;
    }
}

__device__ __forceinline__ void kp_block(const float* __restrict__ a,
                                         const float* __restrict__ b, int n,
                                         float (&red)[256], float* __restrict__ wslot)
{
    int tid = threadIdx.x;
    float s = 0.0f;
    for (int i = tid; i < n; i += 256) {
        float d = a[i] - b[i];
        s = fmaf(d, d, s);
    }
    for (int off = 32; off > 0; off >>= 1) s += __shfl_down(s, off, 64);
    if ((tid & 63) == 0) red[tid >> 6] = s;
    __syncthreads();
    if (tid == 0) *wslot = (red[0] + red[1] + red[2] + red[3]) / (float)n;
}

__global__ __launch_bounds__(256) void fused_all(
    const float* __restrict__ pred, const float* __restrict__ target, int nkp,
    const float* __restrict__ coarse, int Nc,
    const float* __restrict__ fine, int Nf,
    const float* __restrict__ gt, int M,
    int r1, int r2, int r3, int r4,
    float sc_f1, float sc_f2, float sc_c2, float sc_c1,
    float* __restrict__ ws)
{
    __shared__ __align__(16) float sb[4][BTILE];
    __shared__ float red[256];
    const int bid = blockIdx.x;
    float* wslot = ws + bid;

    if (bid < r1)
        chamfer_block<true,  false>(fine,   Nf, gt,     M,  bid,      sc_f1, sb, red, wslot);
    else if (bid < r2)
        chamfer_block<false, true >(gt,     M,  fine,   Nf, bid - r1, sc_f2, sb, red, wslot);
    else if (bid < r3)
        chamfer_block<false, true >(gt,     M,  coarse, Nc, bid - r2, sc_c2, sb, red, wslot);
    else if (bid < r4)
        chamfer_block<true,  false>(coarse, Nc, gt,     M,  bid - r3, sc_c1, sb, red, wslot);
    else
        kp_block(pred, target, nkp, red, wslot);
}

__global__ __launch_bounds__(256) void finalize(const float* __restrict__ ws, int n,
                                                float* __restrict__ out)
{
    int tid = threadIdx.x;
    float s = 0.0f;
    for (int i = tid; i < n; i += 256) s += ws[i];
    for (int off = 32; off > 0; off >>= 1) s += __shfl_down(s, off, 64);
    __shared__ float r[4];
    if ((tid & 63) == 0) r[tid >> 6] = s;
    __syncthreads();
    if (tid == 0) out[0] = r[0] + r[1] + r[2] + r[3];
}

extern "C" void kernel_launch(void* const* d_in, const int* in_sizes, int n_in,
                              void* d_out, int out_size, void* d_ws, size_t ws_size,
                              hipStream_t stream) {
    const float* pred   = (const float*)d_in[0];
    const float* target = (const float*)d_in[1];
    const float* coarse = (const float*)d_in[2]; // [B,3,Nc]
    const float* fine   = (const float*)d_in[3]; // [B,3,Nf]
    const float* gt     = (const float*)d_in[4]; // [B,M,3]
    float* out = (float*)d_out;
    float* ws  = (float*)d_ws;

    const int nkp = in_sizes[0];            // 240
    const int B   = nkp / 30;               // 8
    const int Nc  = in_sizes[2] / (3 * B);  // 1024
    const int Nf  = in_sizes[3] / (3 * B);  // 4096
    const int M   = in_sizes[4] / (3 * B);  // 4096

    const int nb_f1 = B * (Nf / APB);
    const int nb_f2 = B * (M  / APB);
    const int nb_c2 = B * (M  / APB);
    const int nb_c1 = B * (Nc / APB);
    const int r1 = nb_f1;
    const int r2 = r1 + nb_f2;
    const int r3 = r2 + nb_c2;
    const int r4 = r3 + nb_c1;
    const int nb = r4 + 1;                  // +1 kp block

    fused_all<<<nb, 256, 0, stream>>>(
        pred, target, nkp, coarse, Nc, fine, Nf, gt, M,
        r1, r2, r3, r4,
        1.0f / (B * Nf), 1.0f / (B * M), 1.0f / (B * M), 1.0f / (B * Nc),
        ws);
    finalize<<<1, 256, 0, stream>>>(ws, nb, out);
}